// Round 5
// baseline (511.665 us; speedup 1.0000x reference)
//
#include <hip/hip_runtime.h>
#include <stdint.h>

#define LDIFF 0.24f

constexpr int H = 512, W = 512, NB = 2;
constexpr int HW = H * W;              // 262144 = 2^18
constexpr int N_D = NB * HW;           // 524288
constexpr int CVH = 511, CVW = 512;
constexpr int CHH = 512, CHW = 511;
constexpr int N_CV = NB * CVH * CVW;   // 523264
constexpr int NBLKS = 11;              // 11x11 block grid, step 48

// LLC-coherent (cross-XCD) scalar access: relaxed agent atomics compile to
// sc1 loads/stores that read/write through to the die-level Infinity Cache.
__device__ inline float ldc(const float* p) {
    return __hip_atomic_load(p, __ATOMIC_RELAXED, __HIP_MEMORY_SCOPE_AGENT);
}
__device__ inline void stc(float* p, float v) {
    __hip_atomic_store(p, v, __ATOMIC_RELAXED, __HIP_MEMORY_SCOPE_AGENT);
}

// ---------------- cv / ch (written straight into d_out) + depth copy + sync init ----
// NOTE: shift is dropped everywhere: all downstream ops preserve additive
// constants exactly, so y_pred = F(initial+shift)-shift == F(initial).
__global__ void kcvch(const float* __restrict__ guide, const float* __restrict__ initial,
                      float* __restrict__ cv, float* __restrict__ ch, float* __restrict__ D,
                      int* __restrict__ sync) {
    int idx = blockIdx.x * 256 + threadIdx.x;   // < 524288
    if (idx < 512) sync[idx] = 0;               // flags[0..241] + cnt[256..263]
    int b = idx >> 18;
    int yx = idx & (HW - 1);
    int y = yx >> 9, x = yx & 511;
    const float* g = guide + (size_t)b * 3 * HW + yx;
    const float kinv = 1.0f / (0.03f * 0.03f);
    D[idx] = initial[idx];
    if (y < 511) {
        float d = (fabsf(g[512] - g[0]) + fabsf(g[HW + 512] - g[HW]) + fabsf(g[2 * HW + 512] - g[2 * HW])) * (1.0f / 3.0f);
        cv[b * CVH * CVW + y * CVW + x] = 1.0f / (1.0f + d * d * kinv);
    }
    if (x < 511) {
        float d = (fabsf(g[1] - g[0]) + fabsf(g[HW + 1] - g[HW]) + fabsf(g[2 * HW + 1] - g[2 * HW])) * (1.0f / 3.0f);
        ch[b * CHH * CHW + y * CHW + x] = 1.0f / (1.0f + d * d * kinv);
    }
}

// ---------------- single-launch wavefront: params + periodic stencil + blend ----------------
// Block (b,i,j). Deps: (i,j-1),(i-1,j-1),(i-1,j),(i-1,j+1). 242 blocks co-resident.
// Fence-free protocol: depth tile I/O via sc1 (LLC-coherent) relaxed atomics;
// producer drains with s_waitcnt vmcnt(0) then relaxed flag store; consumer
// polls relaxed. No buffer_inv / buffer_wbl2 anywhere on the critical path.
__global__ __launch_bounds__(256) void kwave(float* __restrict__ depth,
                                             const float* __restrict__ cv,
                                             const float* __restrict__ ch,
                                             int* __restrict__ flags) {
    __shared__ float pool[8712];      // aliased: {cvT[4356], chT[4356]} then {A[4096], Bs[4096]}
    __shared__ float sm[256];
    __shared__ float prmS[3];
    __shared__ float xT[4][64];
    __shared__ float xB[4][64];
    float* cvT = pool;
    float* chT = pool + 4356;
    float* A   = pool;
    float* Bs  = pool + 4096;

    int idx = blockIdx.x;            // 0..120
    int i = idx / NBLKS, j = idx % NBLKS;
    int b = blockIdx.y;
    int tid = threadIdx.x;
    int y0 = i * 48, x0 = j * 48;
    int y1 = min(y0 + 64, 512), x1 = min(x0 + 64, 512);
    int bh = y1 - y0, bw = x1 - x0;
    const float* cvb = cv + b * CVH * CVW;
    const float* chb = ch + b * CHH * CHW;

    // ---- stage 66x66 cv/ch tiles (rows y0-1..y0+64, cols x0-1..x0+64; zero at array edges) ----
    for (int p = tid; p < 66 * 66; p += 256) {
        int rr = p / 66, cc = p - rr * 66;
        int y = y0 - 1 + rr, x = x0 - 1 + cc;
        cvT[p] = (y >= 0 && y < 511 && x >= 0 && x < 512) ? cvb[y * CVW + x] : 0.0f;
        chT[p] = (y >= 0 && y < 512 && x >= 0 && x < 511) ? chb[y * CHW + x] : 0.0f;
    }
    __syncthreads();

    // ---- per-block params from LDS ----
    float scv = 0.f, sch = 0.f, sun = 0.f;
    {
        int n = (bh - 1) * bw;
        for (int p = tid; p < n; p += 256) { int r = p / bw, c = p - r * bw; scv += cvT[(r + 1) * 66 + c + 1]; }
    }
    {
        int cols = bw - 1, n = bh * cols;
        for (int p = tid; p < n; p += 256) { int r = p / cols, c = p - r * cols; sch += chT[(r + 1) * 66 + c + 1]; }
    }
    int ur = min(y1, 511) - y0, uc = min(x1, 511) - x0;
    {
        int n = ur * uc;
        for (int p = tid; p < n; p += 256) {
            int r = p / uc, c = p - r * uc;
            float s1 = 0.f, s2 = 0.f, t1 = 0.f, t2 = 0.f;
            #pragma unroll
            for (int dy = 0; dy < 3; dy++)
                #pragma unroll
                for (int dx = 0; dx < 3; dx++) {
                    float v = cvT[(r + dy) * 66 + c + dx]; s1 += v; s2 += v * v;
                    float w2 = chT[(r + dy) * 66 + c + dx]; t1 += w2; t2 += w2 * w2;
                }
            float m = s1 * (1.0f / 9.0f);
            float vcv = s2 * (1.0f / 9.0f) - m * m;
            m = t1 * (1.0f / 9.0f);
            float vch = t2 * (1.0f / 9.0f) - m * m;
            if (vcv < 0.1f && vch < 0.1f) sun += 1.f;
        }
    }
    sm[tid] = scv; __syncthreads();
    for (int s = 128; s; s >>= 1) { if (tid < s) sm[tid] += sm[tid + s]; __syncthreads(); }
    if (tid == 0) prmS[0] = sm[0] / (float)((bh - 1) * bw);
    __syncthreads();
    sm[tid] = sch; __syncthreads();
    for (int s = 128; s; s >>= 1) { if (tid < s) sm[tid] += sm[tid + s]; __syncthreads(); }
    if (tid == 0) prmS[1] = sm[0] / (float)(bh * (bw - 1));
    __syncthreads();
    sm[tid] = sun; __syncthreads();
    for (int s = 128; s; s >>= 1) { if (tid < s) sm[tid] += sm[tid + s]; __syncthreads(); }
    if (tid == 0) prmS[2] = (sm[0] / (float)(ur * uc) > 0.7f) ? 1.0f : 0.0f;
    __syncthreads();

    int me = b * 121 + idx;
    if (prmS[2] <= 0.5f) {
        // no write -> signal immediately (nothing of ours to publish)
        if (tid == 0) __hip_atomic_store(&flags[me], 1, __ATOMIC_RELAXED, __HIP_MEMORY_SCOPE_AGENT);
        return;
    }

    // ---- wait dependencies: relaxed sc1 polls (read-through, no invalidates) ----
    if (tid < 4) {
        int di = (tid == 0) ? i : i - 1;
        int dj = (tid == 0) ? j - 1 : j - 2 + tid;   // tid1->j-1, tid2->j, tid3->j+1
        if (di >= 0 && dj >= 0 && dj < NBLKS) {
            int d = b * 121 + di * NBLKS + dj;
            while (__hip_atomic_load(&flags[d], __ATOMIC_RELAXED, __HIP_MEMORY_SCOPE_AGENT) == 0)
                __builtin_amdgcn_s_sleep(1);
        }
    }
    __syncthreads();

    float a = LDIFF * prmS[0], bc = LDIFF * prmS[1];
    float* base = depth + b * HW;
    int lane = tid & 63, wv = tid >> 6, r0 = wv * 16;

    if (bh == 64 && bw == 64) {
        // ---- fast path: registers + shfl, periodic 64x64; sc1 tile I/O ----
        float u[16], orig[16];
        #pragma unroll
        for (int k = 0; k < 16; k++) { orig[k] = ldc(&base[(y0 + r0 + k) * W + x0 + lane]); u[k] = orig[k]; }
        for (int it = 0; it < 10; it++) {
            xT[wv][lane] = u[0];
            xB[wv][lane] = u[15];
            __syncthreads();
            float ub = xB[(wv + 3) & 3][lane];   // row r0-1 (periodic)
            float ut = xT[(wv + 1) & 3][lane];   // row r0+16 (periodic)
            float nu[16];
            #pragma unroll
            for (int k = 0; k < 16; k++) {
                float up = (k == 0) ? ub : u[k - 1];
                float dn = (k == 15) ? ut : u[k + 1];
                float lf = __shfl(u[k], (lane + 63) & 63);
                float rt = __shfl(u[k], (lane + 1) & 63);
                nu[k] = u[k] + a * (up + dn - 2.0f * u[k]) + bc * (lf + rt - 2.0f * u[k]);
            }
            #pragma unroll
            for (int k = 0; k < 16; k++) u[k] = nu[k];
            __syncthreads();
        }
        float bxw = (x0 > 0 && lane < 16) ? (float)lane * (1.0f / 16.0f) : 1.0f;
        #pragma unroll
        for (int k = 0; k < 16; k++) {
            int r = r0 + k;
            float byw = (y0 > 0 && r < 16) ? (float)r * (1.0f / 16.0f) : 1.0f;
            float wgt = byw * bxw;
            stc(&base[(y0 + r) * W + x0 + lane], orig[k] * (1.0f - wgt) + u[k] * wgt);
        }
    } else {
        // ---- LDS fallback for 32-sized edge blocks (sc1 tile I/O) ----
        int lw = (bw == 64) ? 6 : 5;
        int mw = bw - 1, mh = bh - 1;
        int n = bh * bw;
        for (int p = tid; p < n; p += 256) {
            int r = p >> lw, c = p & mw;
            A[p] = ldc(&base[(y0 + r) * W + x0 + c]);
        }
        __syncthreads();
        float* src = A; float* dst = Bs;
        for (int s = 0; s < 10; s++) {
            for (int p = tid; p < n; p += 256) {
                int r = p >> lw, c = p & mw;
                float u = src[p];
                float up = src[(((r - 1) & mh) << lw) + c];
                float dn = src[(((r + 1) & mh) << lw) + c];
                float lf = src[(r << lw) + ((c - 1) & mw)];
                float rt = src[(r << lw) + ((c + 1) & mw)];
                dst[p] = u + a * (up + dn - 2.0f * u) + bc * (lf + rt - 2.0f * u);
            }
            __syncthreads();
            float* tmp = src; src = dst; dst = tmp;
        }
        for (int p = tid; p < n; p += 256) {
            int r = p >> lw, c = p & mw;
            float by = (y0 > 0 && r < 16) ? (float)r * (1.0f / 16.0f) : 1.0f;
            float bx = (x0 > 0 && c < 16) ? (float)c * (1.0f / 16.0f) : 1.0f;
            float wgt = by * bx;
            int g = (y0 + r) * W + x0 + c;
            float orig = ldc(&base[g]);
            stc(&base[g], orig * (1.0f - wgt) + src[p] * wgt);
        }
    }
    // every wave drains its own sc1 stores to the LLC, then one flag store
    asm volatile("s_waitcnt vmcnt(0)" ::: "memory");
    __syncthreads();
    if (tid == 0) __hip_atomic_store(&flags[me], 1, __ATOMIC_RELAXED, __HIP_MEMORY_SCOPE_AGENT);
}

// ---------------- 64 diffusion iterations in ONE launch ----------------
// 8 rounds x 8 fused micro-iterations; grid barrier between rounds.
// Tile 64x64 (output 48x48, halo 8). Wave wv owns rows [16wv,16wv+16), col = lane.
// cv/ch fragments loaded once (iteration-invariant). Rounds ping-pong D <-> T
// with sc1 I/O; final round writes y_pred with normal stores.
__global__ __launch_bounds__(256) void kdiff64(const float* __restrict__ D,
                                               float* __restrict__ T0, float* __restrict__ T1,
                                               const float* __restrict__ cv,
                                               const float* __restrict__ ch,
                                               float* __restrict__ ypred,
                                               int* __restrict__ cnt) {
    __shared__ float xT[4][64];
    __shared__ float xB[4][64];
    __shared__ float cvB[4][64];
    int bx = blockIdx.x, by = blockIdx.y, b = blockIdx.z;
    int gy0 = by * 48 - 8, gx0 = bx * 48 - 8;
    int tid = threadIdx.x;
    int lane = tid & 63, wv = tid >> 6, r0 = wv * 16;
    const float* cvb = cv + b * CVH * CVW;
    const float* chb = ch + b * CHH * CHW;
    int cx = gx0 + lane;
    int gxc = min(max(cx, 0), 511);
    bool xvalid = (cx >= 0 && cx < 512);

    float cvr[16], chr[16], chl[16];
    int gy[16];
    #pragma unroll
    for (int k = 0; k < 16; k++) {
        int cy = gy0 + r0 + k;
        gy[k] = min(max(cy, 0), 511);
        cvr[k] = (cy >= 0 && cy < 511 && xvalid) ? cvb[cy * CVW + cx] : 0.0f;
        chr[k] = (cy >= 0 && cy < 512 && xvalid && cx < 511) ? chb[cy * CHW + cx] : 0.0f;
    }
    cvB[wv][lane] = cvr[15];
    #pragma unroll
    for (int k = 0; k < 16; k++) {
        float v = __shfl(chr[k], (lane + 63) & 63);
        chl[k] = (lane == 0) ? 0.0f : v;    // tile col -1: halo, coeff 0
    }
    __syncthreads();
    float cvm1 = (wv == 0) ? 0.0f : cvB[wv - 1][lane];   // cv at tile row r0-1

    const float* src = D + b * HW;    // round 0: kwave output (post-dispatch-boundary: normal loads OK)
    float* pp[2] = { T0 + b * HW, T1 + b * HW };

    for (int round = 0; round < 8; round++) {
        float u[16];
        if (round == 0) {
            #pragma unroll
            for (int k = 0; k < 16; k++) u[k] = src[gy[k] * W + gxc];
        } else {
            const float* s = pp[(round - 1) & 1];
            #pragma unroll
            for (int k = 0; k < 16; k++) u[k] = ldc(&s[gy[k] * W + gxc]);
        }

        for (int it = 0; it < 8; it++) {
            xT[wv][lane] = u[0];
            xB[wv][lane] = u[15];
            __syncthreads();
            float ub = (wv > 0) ? xB[wv - 1][lane] : u[0];
            float ut = (wv < 3) ? xT[wv + 1][lane] : u[15];
            float V[16];
            #pragma unroll
            for (int k = 0; k < 16; k++) {
                float up = (k == 0) ? ub : u[k - 1];
                float dn = (k == 15) ? ut : u[k + 1];
                float cup = (k == 0) ? cvm1 : cvr[k - 1];
                V[k] = u[k] + LDIFF * cvr[k] * (dn - u[k]) - LDIFF * cup * (u[k] - up);
            }
            #pragma unroll
            for (int k = 0; k < 16; k++) {
                float lf = __shfl(V[k], (lane + 63) & 63);
                float rt = __shfl(V[k], (lane + 1) & 63);
                u[k] = V[k] + LDIFF * chr[k] * (rt - V[k]) - LDIFF * chl[k] * (V[k] - lf);
            }
            __syncthreads();
        }

        // write central 48x48 (clipped)
        bool cok = (lane >= 8 && lane < 56 && gx0 + lane < 512);
        if (round < 7) {
            float* d = pp[round & 1];
            if (cok) {
                #pragma unroll
                for (int k = 0; k < 16; k++) {
                    int r = r0 + k;
                    if (r >= 8 && r < 56) {
                        int y = gy0 + r;
                        if (y < 512) stc(&d[y * W + gx0 + lane], u[k]);
                    }
                }
            }
            // grid barrier: drain own sc1 stores, then count
            asm volatile("s_waitcnt vmcnt(0)" ::: "memory");
            __syncthreads();
            if (tid == 0) {
                int* c = cnt + round;
                __hip_atomic_fetch_add(c, 1, __ATOMIC_RELAXED, __HIP_MEMORY_SCOPE_AGENT);
                while (__hip_atomic_load(c, __ATOMIC_RELAXED, __HIP_MEMORY_SCOPE_AGENT) < NB * 121)
                    __builtin_amdgcn_s_sleep(1);
            }
            __syncthreads();
        } else {
            float* d = ypred + b * HW;
            if (cok) {
                #pragma unroll
                for (int k = 0; k < 16; k++) {
                    int r = r0 + k;
                    if (r >= 8 && r < 56) {
                        int y = gy0 + r;
                        if (y < 512) d[y * W + gx0 + lane] = u[k];
                    }
                }
            }
        }
    }
}

extern "C" void kernel_launch(void* const* d_in, const int* in_sizes, int n_in,
                              void* d_out, int out_size, void* d_ws, size_t ws_size,
                              hipStream_t stream) {
    const float* guide   = (const float*)d_in[0];
    const float* initial = (const float*)d_in[1];
    float* y_pred = (float*)d_out;
    float* cv = y_pred + N_D;          // output 1
    float* ch = cv + N_CV;             // output 2

    uint8_t* w = (uint8_t*)d_ws;
    int* sync = (int*)w;                                 // flags[0..241], cnt at [256..263]
    int* flags = sync;
    int* cnt = sync + 256;
    float* D  = (float*)(w + 2048);                      // 2 MB depth
    float* T0 = (float*)(w + 2048 + (size_t)N_D * 4);    // 2 MB ping
    float* T1 = (float*)(w + 2048 + (size_t)2 * N_D * 4);// 2 MB pong

    kcvch<<<N_D / 256, 256, 0, stream>>>(guide, initial, cv, ch, D, sync);
    kwave<<<dim3(121, 2), 256, 0, stream>>>(D, cv, ch, flags);
    kdiff64<<<dim3(NBLKS, NBLKS, 2), 256, 0, stream>>>(D, T0, T1, cv, ch, y_pred, cnt);
}

// Round 6
// 351.331 us; speedup vs baseline: 1.4564x; 1.4564x over previous
//
#include <hip/hip_runtime.h>
#include <stdint.h>

#define LDIFF 0.24f

constexpr int H = 512, W = 512, NB = 2;
constexpr int HW = H * W;              // 2^18
constexpr int N_D = NB * HW;           // 524288
constexpr int CVH = 511, CVW = 512;
constexpr int CHH = 512, CHW = 511;
constexpr int N_CV = NB * CVH * CVW;   // 523264
constexpr int NBLKS = 11;              // 11x11 blocks, step 48
constexpr int NBT = NB * 121;          // 242 workgroups, <= 256 CUs -> co-resident

// LLC-coherent (cross-XCD) scalar access: relaxed agent atomics = sc1 ops that
// read/write through to the Infinity Cache. Validated R4/R5.
__device__ inline float ldc(const float* p) {
    return __hip_atomic_load(p, __ATOMIC_RELAXED, __HIP_MEMORY_SCOPE_AGENT);
}
__device__ inline void stc(float* p, float v) {
    __hip_atomic_store(p, v, __ATOMIC_RELAXED, __HIP_MEMORY_SCOPE_AGENT);
}
__device__ inline void poll_ge(const int* p, int v) {
    while (__hip_atomic_load(p, __ATOMIC_RELAXED, __HIP_MEMORY_SCOPE_AGENT) < v)
        __builtin_amdgcn_s_sleep(2);
}

// wave64 DPP rotations/shifts: VALU pipe, no LDS traffic (replaces ds_bpermute
// __shfl). Direction convention probed at runtime (dirL); kwave's use is
// direction-agnostic (lf+rt symmetric).
__device__ inline float rot_a(float x) {  // presumed lane i <- i-1 (wave_rol1)
    return __int_as_float(__builtin_amdgcn_update_dpp(0, __float_as_int(x), 0x134, 0xf, 0xf, false));
}
__device__ inline float rot_b(float x) {  // presumed lane i <- i+1 (wave_ror1)
    return __int_as_float(__builtin_amdgcn_update_dpp(0, __float_as_int(x), 0x13c, 0xf, 0xf, false));
}
__device__ inline float sh_a(float x) {   // presumed lane i <- i-1, lane0 -> 0 (wave_shl1)
    return __int_as_float(__builtin_amdgcn_update_dpp(0, __float_as_int(x), 0x130, 0xf, 0xf, true));
}
__device__ inline float sh_b(float x) {   // presumed lane i <- i+1, lane63 -> 0 (wave_shr1)
    return __int_as_float(__builtin_amdgcn_update_dpp(0, __float_as_int(x), 0x138, 0xf, 0xf, true));
}

// ======================= ONE kernel for the whole pipeline =======================
// Phases: A) cv/ch + D:=initial  B) global barrier + fence pair  C) per-block
// params  D) wavefront (flag-chained, sc1 depth I/O)  E) diffusion 8x8 iters
// (neighbor-flag chained, pipelines behind the wavefront tail).
__global__ __launch_bounds__(256) void kall(
    const float* __restrict__ guide, const float* __restrict__ initial,
    float* __restrict__ cv, float* __restrict__ ch,
    float* __restrict__ D, float* __restrict__ T0, float* __restrict__ T1,
    float* __restrict__ ypred, int* __restrict__ sync_)
{
    __shared__ float pool[8712];          // cvT[4356] | chT[4356]
    __shared__ float sm[256];
    __shared__ float prmS[3];
    __shared__ float xT[4][64];
    __shared__ float xB[4][64];
    __shared__ float cvB[4][64];
    float* cvT = pool;
    float* chT = pool + 4356;

    int* wflag = sync_;                   // [me*16], 64B-padded
    int* dflag = sync_ + 4096;            // [me*16]
    int* bar   = sync_ + 8192;

    const int blk = blockIdx.x;           // 0..120
    const int i = blk / NBLKS, j = blk % NBLKS;
    const int b = blockIdx.y;
    const int tid = threadIdx.x;
    const int lane = tid & 63, wv = tid >> 6;
    const int r0 = wv * 16;
    const int me = b * 121 + blk;

    // ===== Phase A: cv/ch (normal stores into d_out) + D := initial (sc1) =====
    const float kinv = 1.0f / (0.03f * 0.03f);
    for (int idx = me * 256 + tid; idx < N_D; idx += NBT * 256) {
        int bb = idx >> 18;
        int yx = idx & (HW - 1);
        int y = yx >> 9, x = yx & 511;
        const float* g = guide + (size_t)bb * 3 * HW + yx;
        float g0 = g[0], g1 = g[HW], g2 = g[2 * HW];
        stc(&D[idx], initial[idx]);
        if (y < 511) {
            float d = (fabsf(g[512] - g0) + fabsf(g[HW + 512] - g1) + fabsf(g[2 * HW + 512] - g2)) * (1.0f / 3.0f);
            cv[bb * CVH * CVW + y * CVW + x] = 1.0f / (1.0f + d * d * kinv);
        }
        if (x < 511) {
            float d = (fabsf(g[1] - g0) + fabsf(g[HW + 1] - g1) + fabsf(g[2 * HW + 1] - g2)) * (1.0f / 3.0f);
            ch[bb * CHH * CHW + y * CHW + x] = 1.0f / (1.0f + d * d * kinv);
        }
    }

    // ===== one-shot global barrier with release/acquire pair =====
    __syncthreads();
    if (tid == 0) {
        __hip_atomic_fetch_add(bar, 1, __ATOMIC_ACQ_REL, __HIP_MEMORY_SCOPE_AGENT);
        while (__hip_atomic_load(bar, __ATOMIC_RELAXED, __HIP_MEMORY_SCOPE_AGENT) < NBT)
            __builtin_amdgcn_s_sleep(8);
    }
    __syncthreads();
    __builtin_amdgcn_fence(__ATOMIC_ACQUIRE, "agent");   // cv/ch now visible to normal loads

    // ===== Phase C: per-block params (normal, cached loads) =====
    const int y0 = i * 48, x0 = j * 48;
    const int y1 = min(y0 + 64, 512), x1 = min(x0 + 64, 512);
    const int bh = y1 - y0, bw = x1 - x0;
    const float* cvb = cv + b * CVH * CVW;
    const float* chb = ch + b * CHH * CHW;

    for (int p = tid; p < 66 * 66; p += 256) {
        int rr = p / 66, c2 = p - rr * 66;
        int y = y0 - 1 + rr, x = x0 - 1 + c2;
        cvT[p] = (y >= 0 && y < 511 && x >= 0 && x < 512) ? cvb[y * CVW + x] : 0.0f;
        chT[p] = (y >= 0 && y < 512 && x >= 0 && x < 511) ? chb[y * CHW + x] : 0.0f;
    }
    __syncthreads();

    float scv = 0.f, sch = 0.f, sun = 0.f;
    {
        int n = (bh - 1) * bw;
        for (int p = tid; p < n; p += 256) { int r = p / bw, c = p - r * bw; scv += cvT[(r + 1) * 66 + c + 1]; }
    }
    {
        int cols = bw - 1, n = bh * cols;
        for (int p = tid; p < n; p += 256) { int r = p / cols, c = p - r * cols; sch += chT[(r + 1) * 66 + c + 1]; }
    }
    const int ur = min(y1, 511) - y0, uc = min(x1, 511) - x0;
    {
        int n = ur * uc;
        for (int p = tid; p < n; p += 256) {
            int r = p / uc, c = p - r * uc;
            float s1 = 0.f, s2 = 0.f, t1 = 0.f, t2 = 0.f;
            #pragma unroll
            for (int dy = 0; dy < 3; dy++)
                #pragma unroll
                for (int dx = 0; dx < 3; dx++) {
                    float v = cvT[(r + dy) * 66 + c + dx]; s1 += v; s2 += v * v;
                    float w2 = chT[(r + dy) * 66 + c + dx]; t1 += w2; t2 += w2 * w2;
                }
            float m = s1 * (1.0f / 9.0f);
            float vcv = s2 * (1.0f / 9.0f) - m * m;
            m = t1 * (1.0f / 9.0f);
            float vch = t2 * (1.0f / 9.0f) - m * m;
            if (vcv < 0.1f && vch < 0.1f) sun += 1.f;
        }
    }
    sm[tid] = scv; __syncthreads();
    for (int s = 128; s; s >>= 1) { if (tid < s) sm[tid] += sm[tid + s]; __syncthreads(); }
    if (tid == 0) prmS[0] = sm[0] / (float)((bh - 1) * bw);
    __syncthreads();
    sm[tid] = sch; __syncthreads();
    for (int s = 128; s; s >>= 1) { if (tid < s) sm[tid] += sm[tid + s]; __syncthreads(); }
    if (tid == 0) prmS[1] = sm[0] / (float)(bh * (bw - 1));
    __syncthreads();
    sm[tid] = sun; __syncthreads();
    for (int s = 128; s; s >>= 1) { if (tid < s) sm[tid] += sm[tid + s]; __syncthreads(); }
    if (tid == 0) prmS[2] = (sm[0] / (float)(ur * uc) > 0.7f) ? 1.0f : 0.0f;
    __syncthreads();

    const bool docond = prmS[2] > 0.5f;
    if (tid == 0 && !docond)
        __hip_atomic_store(&wflag[me * 16], 1, __ATOMIC_RELAXED, __HIP_MEMORY_SCOPE_AGENT);

    // DPP direction probe (wave-uniform)
    int pr = __builtin_amdgcn_update_dpp(0, lane, 0x134, 0xf, 0xf, false);
    const bool dirL = (pr == ((lane + 63) & 63));   // true: rot_a gives lane-1's value

    float* Db = D + b * HW;
    const float* ini = initial + b * HW;

    // ===== Phase D: wavefront block (periodic stencil, blend) =====
    // Replication trick: bh/bw==32 blocks embed 32-periodic data in the 64-wide
    // register layout (identical math, one code path). Interior pixels (never
    // written by predecessors) load from `initial` BEFORE the dep wait; strip
    // pixels (top 16 rows if i>0, left 16 cols if j>0) load from D (sc1) after.
    if (docond) {
        const float a = LDIFF * prmS[0], bc = LDIFF * prmS[1];
        const int mh = bh - 1, mw = bw - 1;
        const int cc = lane & mw;
        float u[16], orig[16];
        int addr[16]; bool fD[16];
        #pragma unroll
        for (int k = 0; k < 16; k++) {
            int rr = (r0 + k) & mh;
            addr[k] = (y0 + rr) * W + x0 + cc;
            fD[k] = (i > 0 && rr < 16) || (j > 0 && cc < 16);
            if (!fD[k]) orig[k] = ini[addr[k]];
        }
        if (tid < 4) {
            int di = (tid == 0) ? i : i - 1;
            int dj = (tid == 0) ? j - 1 : j - 2 + tid;   // tid1:j-1 tid2:j tid3:j+1
            if (di >= 0 && dj >= 0 && dj < NBLKS)
                poll_ge(&wflag[(b * 121 + di * NBLKS + dj) * 16], 1);
        }
        __syncthreads();
        #pragma unroll
        for (int k = 0; k < 16; k++) if (fD[k]) orig[k] = ldc(&Db[addr[k]]);
        #pragma unroll
        for (int k = 0; k < 16; k++) u[k] = orig[k];

        for (int it = 0; it < 10; it++) {
            xT[wv][lane] = u[0];
            xB[wv][lane] = u[15];
            __syncthreads();
            float ub = xB[(wv + 3) & 3][lane];   // row r0-1 (periodic)
            float ut = xT[(wv + 1) & 3][lane];   // row r0+16 (periodic)
            float nu[16];
            #pragma unroll
            for (int k = 0; k < 16; k++) {
                float up = (k == 0) ? ub : u[k - 1];
                float dn = (k == 15) ? ut : u[k + 1];
                float hsum = rot_a(u[k]) + rot_b(u[k]);   // lf+rt, direction-agnostic
                nu[k] = u[k] + a * (up + dn - 2.0f * u[k]) + bc * (hsum - 2.0f * u[k]);
            }
            #pragma unroll
            for (int k = 0; k < 16; k++) u[k] = nu[k];
            __syncthreads();
        }

        if (lane < bw) {
            float bxw = (x0 > 0 && lane < 16) ? (float)lane * (1.0f / 16.0f) : 1.0f;
            #pragma unroll
            for (int k = 0; k < 16; k++) {
                int r = r0 + k;
                if (r < bh) {
                    float byw = (y0 > 0 && r < 16) ? (float)r * (1.0f / 16.0f) : 1.0f;
                    float wgt = byw * bxw;
                    stc(&Db[(y0 + r) * W + x0 + lane], orig[k] * (1.0f - wgt) + u[k] * wgt);
                }
            }
        }
        asm volatile("s_waitcnt vmcnt(0)" ::: "memory");
        __syncthreads();
        if (tid == 0)
            __hip_atomic_store(&wflag[me * 16], 1, __ATOMIC_RELAXED, __HIP_MEMORY_SCOPE_AGENT);
    }

    // ===== Phase E: diffusion, 8 stages x 8 iters, neighbor-flag chained =====
    // Tile 64x64 (core 48x48 + halo 8); halo deps are the 3x3 block neighborhood,
    // so stages chain on local flags -- no global barrier; pipelines behind the
    // wavefront tail. sc1 I/O for u; cv/ch fragments cached normal loads.
    const int gy0 = y0 - 8, gx0 = x0 - 8;
    const int cx = gx0 + lane;
    const int gxc = min(max(cx, 0), 511);
    const bool xv = (cx >= 0 && cx < 512);
    float cvr[16], chr[16], chl[16];
    int gyA[16];
    #pragma unroll
    for (int k = 0; k < 16; k++) {
        int cy = gy0 + r0 + k;
        gyA[k] = min(max(cy, 0), 511);
        cvr[k] = (cy >= 0 && cy < 511 && xv) ? cvb[cy * CVW + cx] : 0.0f;
        chr[k] = (cy >= 0 && cy < 512 && xv && cx < 511) ? chb[cy * CHW + cx] : 0.0f;
        chl[k] = dirL ? sh_a(chr[k]) : sh_b(chr[k]);   // left-neighbor coeff, 0 at lane edge
    }
    cvB[wv][lane] = cvr[15];
    __syncthreads();
    const float cvm1 = (wv == 0) ? 0.0f : cvB[wv - 1][lane];

    float* Tb0 = T0 + b * HW;
    float* Tb1 = T1 + b * HW;
    float* ypb = ypred + b * HW;
    const bool cok = (lane >= 8 && lane < 56 && gx0 + lane < 512);

    for (int t = 1; t <= 8; t++) {
        if (tid < 9) {
            int di = tid / 3 - 1, dj = tid % 3 - 1;
            if (di != 0 || dj != 0) {
                int ni = i + di, nj = j + dj;
                if (ni >= 0 && ni < NBLKS && nj >= 0 && nj < NBLKS) {
                    int nb = (b * 121 + ni * NBLKS + nj) * 16;
                    if (t == 1) poll_ge(&wflag[nb], 1);
                    else        poll_ge(&dflag[nb], t - 1);
                }
            }
        }
        __syncthreads();
        const float* src = (t == 1) ? Db : (((t - 1) & 1) ? Tb1 : Tb0);
        float u[16];
        #pragma unroll
        for (int k = 0; k < 16; k++) u[k] = ldc(&src[gyA[k] * W + gxc]);

        for (int it = 0; it < 8; it++) {
            xT[wv][lane] = u[0];
            xB[wv][lane] = u[15];
            __syncthreads();
            float ub = (wv > 0) ? xB[wv - 1][lane] : u[0];
            float ut = (wv < 3) ? xT[wv + 1][lane] : u[15];
            float V[16];
            #pragma unroll
            for (int k = 0; k < 16; k++) {
                float up = (k == 0) ? ub : u[k - 1];
                float dn = (k == 15) ? ut : u[k + 1];
                float cup = (k == 0) ? cvm1 : cvr[k - 1];
                V[k] = u[k] + LDIFF * cvr[k] * (dn - u[k]) - LDIFF * cup * (u[k] - up);
            }
            #pragma unroll
            for (int k = 0; k < 16; k++) {
                float rA = rot_a(V[k]);
                float rB = rot_b(V[k]);
                float lf = dirL ? rA : rB;
                float rt = dirL ? rB : rA;
                u[k] = V[k] + LDIFF * chr[k] * (rt - V[k]) - LDIFF * chl[k] * (V[k] - lf);
            }
            __syncthreads();
        }

        if (t < 8) {
            float* dst = (t & 1) ? Tb1 : Tb0;
            if (cok) {
                #pragma unroll
                for (int k = 0; k < 16; k++) {
                    int r = r0 + k;
                    if (r >= 8 && r < 56) {
                        int y = gy0 + r;
                        if (y < 512) stc(&dst[y * W + gx0 + lane], u[k]);
                    }
                }
            }
            asm volatile("s_waitcnt vmcnt(0)" ::: "memory");
            __syncthreads();
            if (tid == 0)
                __hip_atomic_store(&dflag[me * 16], t, __ATOMIC_RELAXED, __HIP_MEMORY_SCOPE_AGENT);
        } else {
            if (cok) {
                #pragma unroll
                for (int k = 0; k < 16; k++) {
                    int r = r0 + k;
                    if (r >= 8 && r < 56) {
                        int y = gy0 + r;
                        if (y < 512) ypb[y * W + gx0 + lane] = u[k];
                    }
                }
            }
        }
    }
}

extern "C" void kernel_launch(void* const* d_in, const int* in_sizes, int n_in,
                              void* d_out, int out_size, void* d_ws, size_t ws_size,
                              hipStream_t stream) {
    const float* guide   = (const float*)d_in[0];
    const float* initial = (const float*)d_in[1];
    float* y_pred = (float*)d_out;
    float* cv = y_pred + N_D;          // output 1
    float* ch = cv + N_CV;             // output 2

    uint8_t* w = (uint8_t*)d_ws;
    int* sync_ = (int*)w;              // wflag @0, dflag @4096 ints, bar @8192 (64B-padded)
    float* D  = (float*)(w + 36864);
    float* T0 = (float*)(w + 36864 + (size_t)N_D * 4);
    float* T1 = (float*)(w + 36864 + (size_t)2 * N_D * 4);

    hipMemsetAsync(sync_, 0, 36864, stream);
    kall<<<dim3(121, NB), 256, 0, stream>>>(guide, initial, cv, ch, D, T0, T1, y_pred, sync_);
}